// Round 8
// baseline (113.586 us; speedup 1.0000x reference)
//
#include <hip/hip_runtime.h>

#define NEWL 150
#define EMBD 64
#define NCOL 256
#define CIMU 48
#define CEMG 16

#define KSTI 225            // total 32-wide k-steps imu (150*48/32)
#define KSTE 75             // total k-steps emg
#define NCI 5               // imu s-chunks (30 s -> 45 ksteps each)
#define SCH_I 30
#define NG_I 15             // groups per imu chunk (2 s -> 3 ksteps)
#define NG_E 25             // groups per emg chunk (6 s -> 3 ksteps)

typedef __bf16 bf16x8_t __attribute__((ext_vector_type(8)));
typedef __bf16 bf16x4_t __attribute__((ext_vector_type(4)));
typedef float f32x4_t __attribute__((ext_vector_type(4)));

__device__ __forceinline__ f32x4_t mfma16(bf16x8_t a, bf16x8_t b, f32x4_t c) {
  return __builtin_amdgcn_mfma_f32_16x16x32_bf16(a, b, c, 0, 0, 0);
}

// raw barrier: orders LDS only (lgkmcnt), does NOT drain vmcnt ->
// register-destined global prefetches stay in flight across groups.
#define BAR() do {                                          \
    asm volatile("s_waitcnt lgkmcnt(0)" ::: "memory");      \
    __builtin_amdgcn_s_barrier();                           \
    asm volatile("" ::: "memory");                          \
  } while (0)

// ---------- K0: combined weights (both modalities, one w_proj read) + bias partials
// W_pack[cb][ks][lane=h*16+(col&15)][u], k = ks*32 + h*8 + u
template <int C, int KST>
__device__ __forceinline__ void wcomb_body(const float* __restrict__ wemb,
                                           const float* wreg,
                                           __bf16* __restrict__ wpk, int s, int j) {
  const int cb = j >> 4, lr = j & 15;
#pragma unroll
  for (int q = 0; q < C / 8; ++q) {
    const int kq = (s * C) / 8 + q;
    const int ks = kq >> 2, h = kq & 3;
    bf16x8_t tv;
#pragma unroll
    for (int u = 0; u < 8; ++u) {
      const float* we = wemb + (q * 8 + u) * EMBD;
      float acc = 0.f;
#pragma unroll
      for (int e = 0; e < EMBD; ++e) acc = fmaf(we[e], wreg[e], acc);
      tv[u] = (__bf16)acc;
    }
    *(bf16x8_t*)(wpk + (((size_t)cb * KST + ks) * 64 + h * 16 + lr) * 8) = tv;
  }
}

__global__ __launch_bounds__(256) void wcomb_kernel(
    const float* __restrict__ w_emb_imu, const float* __restrict__ w_emb_emg,
    const float* __restrict__ b_emb_imu, const float* __restrict__ b_emb_emg,
    const float* __restrict__ w_proj,
    __bf16* __restrict__ wpk_imu, __bf16* __restrict__ wpk_emg,
    float* __restrict__ bpart) {
  const int s = blockIdx.x, j = threadIdx.x;
  const float* wp_base = w_proj + (size_t)s * EMBD * NCOL + j;
  float wreg[EMBD];
#pragma unroll
  for (int e = 0; e < EMBD; ++e) wreg[e] = wp_base[(size_t)e * NCOL];
  float bi = 0.f, be = 0.f;
#pragma unroll
  for (int e = 0; e < EMBD; ++e) {
    bi = fmaf(b_emb_imu[e], wreg[e], bi);
    be = fmaf(b_emb_emg[e], wreg[e], be);
  }
  bpart[(size_t)s * NCOL + j] = bi;
  bpart[((size_t)NEWL + s) * NCOL + j] = be;
  wcomb_body<CIMU, KSTI>(w_emb_imu, wreg, wpk_imu, s, j);
  wcomb_body<CEMG, KSTE>(w_emb_emg, wreg, wpk_emg, s, j);
}

__global__ __launch_bounds__(256) void bias_kernel(
    const float* __restrict__ b_proj, const float* __restrict__ bpart,
    float* __restrict__ bias) {
  const int m = blockIdx.x, j = threadIdx.x;
  float acc = b_proj[j];
  for (int s = 0; s < NEWL; ++s) acc += bpart[((size_t)m * NEWL + s) * NCOL + j];
  bias[m * NCOL + j] = acc;
}

// ---------- K1: fused ragged-interp + MFMA GEMM (R6 structure + raw barriers)
// Block = 32 rows x 128 cols; 4 waves each 32x32. Gathers issued 2 half-groups
// ahead, B-frags 1 group ahead; raw BAR keeps them in flight.
__global__ __launch_bounds__(256) void fused_kernel(
    const float* __restrict__ x_imu, const float* __restrict__ x_emg,
    const int* __restrict__ lens,
    const __bf16* __restrict__ wpk_imu, const __bf16* __restrict__ wpk_emg,
    const float* __restrict__ bias, float* __restrict__ p_imu,
    float* __restrict__ out, int B, int T) {
  __shared__ __bf16 lds[2][2][3][512];  // [buf][row-plane][ks][lane*8]

  const int bid = blockIdx.x;
  const int span = B >> 4;  // 128 blocks per chunk
  const int mts = B >> 5;   // 64 m-tiles
  const int tid = threadIdx.x;
  const int wv = tid >> 6, l = tid & 63;

  bool is_imu;
  int c, r;
  if (bid < NCI * span) { is_imu = true; c = bid / span; r = bid - c * span; }
  else { is_imu = false; c = 0; r = bid - NCI * span; }
  const int nh = r / mts, mt = r - nh * mts;  // nh-siblings 64 apart -> same XCD

  const __bf16* Wp = is_imu ? wpk_imu : wpk_emg;
  const int KST = is_imu ? KSTI : KSTE;
  const int ks0 = is_imu ? c * 45 : 0;
  const int NG = is_imu ? NG_I : NG_E;
  float* P = is_imu ? (p_imu + (size_t)c * B * NCOL) : (out + (size_t)B * NCOL);

  const size_t PS = (size_t)KST * 512;  // B fragment-plane stride (bf16)
  const __bf16* bg = Wp + ((size_t)(nh * 8 + wv * 2) * KST + ks0) * 512 + l * 8;

  // gather thread mappings
  const int q = tid & 3, sl = (tid >> 2) & 1, bli = tid >> 3;  // imu: 4 thr/(b,s)
  const int ble = tid / 6, se = tid - (tid / 6) * 6;           // emg: 1 thr/(b,s)
  const bool act = is_imu || (tid < 192);
  const int b_g = mt * 32 + (is_imu ? bli : (act ? ble : 0));
  int lenv = 1;
  float scale = 0.f;
  if (act) { lenv = lens[b_g]; scale = (float)lenv * (1.0f / 150.0f); }
  const int prt_i = (l & ~3) | 2 | (q & 1);  // imu lerp partner lane

  float gr[2][32];   // gather reg slots (imu uses 24, emg 32)
  float wS[2];       // lerp weights per slot
  bf16x8_t bB[2][6]; // B fragment slots (2 planes x 3 ksteps)
  f32x4_t acc00 = {0.f, 0.f, 0.f, 0.f}, acc01 = acc00, acc10 = acc00, acc11 = acc00;

#define ISSUE_GI(g2, Pp) do {                                                   \
    const int s_ = c * SCH_I + (g2) * 2 + sl;                                   \
    float src_ = fmaxf(((float)s_ + 0.5f) * scale - 0.5f, 0.0f);                \
    int i0_ = min((int)src_, lenv - 1);                                         \
    int i1_ = min(i0_ + 1, lenv - 1);                                           \
    wS[Pp] = src_ - (float)i0_;                                                 \
    const float* p_ =                                                           \
        x_imu + ((size_t)b_g * T + ((q < 2) ? i0_ : i1_)) * CIMU + (q & 1) * 24;\
    _Pragma("unroll")                                                           \
    for (int t = 0; t < 6; ++t) {                                               \
      float4 v_ = *(const float4*)(p_ + t * 4);                                 \
      gr[Pp][t * 4 + 0] = v_.x; gr[Pp][t * 4 + 1] = v_.y;                       \
      gr[Pp][t * 4 + 2] = v_.z; gr[Pp][t * 4 + 3] = v_.w;                       \
    }                                                                           \
  } while (0)

#define LERP_WI(Pp, BUF) do {                                                   \
    const float wg_ = wS[Pp], om_ = 1.0f - wg_;                                 \
    _Pragma("unroll")                                                           \
    for (int t = 0; t < 6; ++t) {                                               \
      float a0_ = gr[Pp][t * 4 + 0], a1_ = gr[Pp][t * 4 + 1];                   \
      float a2_ = gr[Pp][t * 4 + 2], a3_ = gr[Pp][t * 4 + 3];                   \
      float p0_ = __shfl(a0_, prt_i), p1_ = __shfl(a1_, prt_i);                 \
      float p2_ = __shfl(a2_, prt_i), p3_ = __shfl(a3_, prt_i);                 \
      if (q < 2) {                                                              \
        bf16x4_t o_;                                                            \
        o_[0] = (__bf16)(a0_ * om_ + p0_ * wg_);                                \
        o_[1] = (__bf16)(a1_ * om_ + p1_ * wg_);                                \
        o_[2] = (__bf16)(a2_ * om_ + p2_ * wg_);                                \
        o_[3] = (__bf16)(a3_ * om_ + p3_ * wg_);                                \
        const int kq_ = sl * 6 + q * 3 + (t >> 1);                              \
        *(bf16x4_t*)(&lds[BUF][bli >> 4][kq_ >> 2]                              \
                         [((kq_ & 3) * 16 + (bli & 15)) * 8 + (t & 1) * 4]) = o_;\
      }                                                                         \
    }                                                                           \
  } while (0)

#define ISSUE_GE(g2, Pp) do { if (act) {                                        \
    const int s_ = (g2) * 6 + se;                                               \
    float src_ = fmaxf(((float)s_ + 0.5f) * scale - 0.5f, 0.0f);                \
    int i0_ = min((int)src_, lenv - 1);                                         \
    int i1_ = min(i0_ + 1, lenv - 1);                                           \
    wS[Pp] = src_ - (float)i0_;                                                 \
    const float* p0_ = x_emg + ((size_t)b_g * T + i0_) * CEMG;                  \
    const float* p1_ = x_emg + ((size_t)b_g * T + i1_) * CEMG;                  \
    _Pragma("unroll")                                                           \
    for (int t = 0; t < 4; ++t) {                                               \
      float4 v_ = *(const float4*)(p0_ + t * 4);                                \
      gr[Pp][t * 4 + 0] = v_.x; gr[Pp][t * 4 + 1] = v_.y;                       \
      gr[Pp][t * 4 + 2] = v_.z; gr[Pp][t * 4 + 3] = v_.w;                       \
      float4 u_ = *(const float4*)(p1_ + t * 4);                                \
      gr[Pp][16 + t * 4 + 0] = u_.x; gr[Pp][16 + t * 4 + 1] = u_.y;             \
      gr[Pp][16 + t * 4 + 2] = u_.z; gr[Pp][16 + t * 4 + 3] = u_.w;             \
    }                                                                           \
  } } while (0)

#define LERP_WE(Pp, BUF) do { if (act) {                                        \
    const float wg_ = wS[Pp], om_ = 1.0f - wg_;                                 \
    _Pragma("unroll")                                                           \
    for (int t2 = 0; t2 < 2; ++t2) {                                            \
      bf16x8_t o_;                                                              \
      _Pragma("unroll")                                                         \
      for (int u = 0; u < 8; ++u)                                               \
        o_[u] = (__bf16)(gr[Pp][t2 * 8 + u] * om_ +                             \
                         gr[Pp][16 + t2 * 8 + u] * wg_);                        \
      const int kq_ = se * 2 + t2;                                              \
      *(bf16x8_t*)(&lds[BUF][ble >> 4][kq_ >> 2]                                \
                       [((kq_ & 3) * 16 + (ble & 15)) * 8]) = o_;               \
    }                                                                           \
  } } while (0)

#define ISSUE_B(g1, Ss) do {                                                    \
    const __bf16* pb_ = bg + (size_t)((g1) * 3) * 512;                          \
    _Pragma("unroll")                                                           \
    for (int ks = 0; ks < 3; ++ks) {                                            \
      bB[Ss][ks * 2 + 0] = *(const bf16x8_t*)(pb_ + (size_t)ks * 512);          \
      bB[Ss][ks * 2 + 1] = *(const bf16x8_t*)(pb_ + PS + (size_t)ks * 512);     \
    }                                                                           \
  } while (0)

#define COMPUTE(Pp) do {                                                        \
    _Pragma("unroll")                                                           \
    for (int ks = 0; ks < 3; ++ks) {                                            \
      bf16x8_t a0_ = *(const bf16x8_t*)(&lds[Pp][0][ks][l * 8]);                \
      bf16x8_t a1_ = *(const bf16x8_t*)(&lds[Pp][1][ks][l * 8]);                \
      acc00 = mfma16(a0_, bB[Pp][ks * 2 + 0], acc00);                           \
      acc01 = mfma16(a0_, bB[Pp][ks * 2 + 1], acc01);                           \
      acc10 = mfma16(a1_, bB[Pp][ks * 2 + 0], acc10);                           \
      acc11 = mfma16(a1_, bB[Pp][ks * 2 + 1], acc11);                           \
    }                                                                           \
  } while (0)

  // prologue: 2 gather sets + 1 B set in flight, group 0 staged
  if (is_imu) { ISSUE_GI(0, 0); ISSUE_GI(1, 1); }
  else        { ISSUE_GE(0, 0); ISSUE_GE(1, 1); }
  ISSUE_B(0, 0);
  if (is_imu) LERP_WI(0, 0); else LERP_WE(0, 0);
  BAR();

  for (int gp = 0; gp < (NG_E + 1) / 2; ++gp) {
    const int g = gp * 2;
    if (g >= NG) break;
    {
      if (g + 2 < NG) { if (is_imu) ISSUE_GI(g + 2, 0); else ISSUE_GE(g + 2, 0); }
      if (g + 1 < NG) ISSUE_B(g + 1, 1);
      COMPUTE(0);
      if (g + 1 < NG) { if (is_imu) LERP_WI(1, 1); else LERP_WE(1, 1); }
      BAR();
    }
    if (g + 1 < NG) {
      if (g + 3 < NG) { if (is_imu) ISSUE_GI(g + 3, 1); else ISSUE_GE(g + 3, 1); }
      if (g + 2 < NG) ISSUE_B(g + 2, 0);
      COMPUTE(1);
      if (g + 2 < NG) { if (is_imu) LERP_WI(0, 0); else LERP_WE(0, 0); }
      BAR();
    }
  }

  // epilogue: C/D col = lane&15, row = (lane>>4)*4 + reg; emg adds bias.
  const int lh = l >> 4, lr = l & 15;
  const int colb = nh * 128 + wv * 32;
  float b0 = 0.f, b1 = 0.f;
  if (!is_imu) {
    b0 = bias[NCOL + colb + lr];
    b1 = bias[NCOL + colb + 16 + lr];
  }
  float* Pb = P + (size_t)(mt * 32 + lh * 4) * NCOL + colb + lr;
#pragma unroll
  for (int jj = 0; jj < 4; ++jj) {
    Pb[(size_t)jj * NCOL] = acc00[jj] + b0;
    Pb[(size_t)jj * NCOL + 16] = acc01[jj] + b1;
    Pb[(size_t)(16 + jj) * NCOL] = acc10[jj] + b0;
    Pb[(size_t)(16 + jj) * NCOL + 16] = acc11[jj] + b1;
  }
#undef ISSUE_GI
#undef LERP_WI
#undef ISSUE_GE
#undef LERP_WE
#undef ISSUE_B
#undef COMPUTE
}

// ---------- K2: imu split-K combine + bias -> d_out[0..B*256)
__global__ __launch_bounds__(256) void combine_kernel(
    const float* __restrict__ bias, const float* __restrict__ p_imu,
    float* __restrict__ out, int B) {
  const int b = blockIdx.x, j = threadIdx.x;
  const size_t n = (size_t)B * NCOL;
  const size_t o = (size_t)b * NCOL + j;
  float v = bias[j];
#pragma unroll
  for (int c = 0; c < NCI; ++c) v += p_imu[c * n + o];
  out[o] = v;
}

extern "C" void kernel_launch(void* const* d_in, const int* in_sizes, int n_in,
                              void* d_out, int out_size, void* d_ws, size_t ws_size,
                              hipStream_t stream) {
  const float* x_imu     = (const float*)d_in[0];
  const float* x_emg     = (const float*)d_in[1];
  const int*   lens      = (const int*)d_in[2];
  const float* w_emb_imu = (const float*)d_in[3];
  const float* b_emb_imu = (const float*)d_in[4];
  const float* w_emb_emg = (const float*)d_in[5];
  const float* b_emb_emg = (const float*)d_in[6];
  const float* w_proj    = (const float*)d_in[7];
  const float* b_proj    = (const float*)d_in[8];
  float* out = (float*)d_out;

  const int B = in_sizes[2];
  const int T = in_sizes[0] / (B * CIMU);

  char* ws = (char*)d_ws;
  __bf16* wpk_imu = (__bf16*)ws;  ws += (size_t)NCOL * KSTI * 32 * 2;  // 3.69 MB
  __bf16* wpk_emg = (__bf16*)ws;  ws += (size_t)NCOL * KSTE * 32 * 2;  // 1.23 MB
  float*  bias    = (float*)ws;   ws += 2 * NCOL * 4;
  float*  bpart   = (float*)ws;   ws += (size_t)2 * NEWL * NCOL * 4;
  float*  p_imu   = (float*)ws;   ws += (size_t)NCI * B * NCOL * 4;    // 10.5 MB

  wcomb_kernel<<<NEWL, 256, 0, stream>>>(w_emb_imu, w_emb_emg, b_emb_imu,
                                         b_emb_emg, w_proj, wpk_imu, wpk_emg,
                                         bpart);
  bias_kernel<<<2, 256, 0, stream>>>(b_proj, bpart, bias);
  const int nblk = (NCI + 1) * (B >> 4);  // 768
  fused_kernel<<<nblk, 256, 0, stream>>>(x_imu, x_emg, lens, wpk_imu, wpk_emg,
                                         bias, p_imu, out, B, T);
  combine_kernel<<<B, 256, 0, stream>>>(bias, p_imu, out, B);
}

// Round 9
// 110.035 us; speedup vs baseline: 1.0323x; 1.0323x over previous
//
#include <hip/hip_runtime.h>

#define NEWL 150
#define EMBD 64
#define NCOL 256
#define CIMU 48
#define CEMG 16

#define KIMU (NEWL * CIMU)  // 7200
#define KEMG (NEWL * CEMG)  // 2400
#define KSTI 225            // total k-steps (32-wide) imu
#define KSTE 75             // total k-steps emg
#define NCI 5               // imu s-chunks (30 s each -> 45 ksteps)
#define SCH_I 30
#define NG_I 15             // groups per imu chunk (2 s -> 3 ksteps each)
#define NG_E 25             // groups per emg chunk (6 s -> 3 ksteps each)

typedef __bf16 bf16x8_t __attribute__((ext_vector_type(8)));
typedef __bf16 bf16x4_t __attribute__((ext_vector_type(4)));
typedef float f32x4_t __attribute__((ext_vector_type(4)));

__device__ __forceinline__ f32x4_t mfma16(bf16x8_t a, bf16x8_t b, f32x4_t c) {
  return __builtin_amdgcn_mfma_f32_16x16x32_bf16(a, b, c, 0, 0, 0);
}

// Barrier via fully-modeled builtins (no asm, no memory clobbers):
// lgkmcnt(0) orders this wave's LDS ops; s_barrier syncs waves; vmcnt is NOT
// drained, so register-destined global prefetches stay in flight and the
// waitcnt pass keeps emitting counted vmcnt(N) for their later uses.
// simm16 = 0xC07F: vmcnt=63 (no wait), expcnt=7 (no wait), lgkmcnt=0.
#define BARB() do {                              \
    __builtin_amdgcn_s_waitcnt(0xC07F);          \
    __builtin_amdgcn_s_barrier();                \
  } while (0)

// ---------- K0: combined weights packed in MFMA B-fragment order + bias partials.
// Merged: one block per s reads its w_proj slice ONCE, emits imu+emg packs.
// W_pack[cb][ks][lane=h*16+(col&15)][u]  where k = ks*32 + h*8 + u
template <int C, int KST>
__device__ __forceinline__ void wcomb_body(const float* __restrict__ wemb,
                                           const float* wreg,
                                           __bf16* __restrict__ wpk, int s, int j) {
  const int cb = j >> 4, lr = j & 15;
#pragma unroll
  for (int q = 0; q < C / 8; ++q) {
    const int kq = (s * C) / 8 + q;
    const int ks = kq >> 2, h = kq & 3;
    bf16x8_t tv;
#pragma unroll
    for (int u = 0; u < 8; ++u) {
      const float* we = wemb + (q * 8 + u) * EMBD;
      float acc = 0.f;
#pragma unroll
      for (int e = 0; e < EMBD; ++e) acc = fmaf(we[e], wreg[e], acc);
      tv[u] = (__bf16)acc;
    }
    *(bf16x8_t*)(wpk + (((size_t)cb * KST + ks) * 64 + h * 16 + lr) * 8) = tv;
  }
}

__global__ __launch_bounds__(256) void wcomb_kernel(
    const float* __restrict__ w_emb_imu, const float* __restrict__ w_emb_emg,
    const float* __restrict__ b_emb_imu, const float* __restrict__ b_emb_emg,
    const float* __restrict__ w_proj,
    __bf16* __restrict__ wpk_imu, __bf16* __restrict__ wpk_emg,
    float* __restrict__ bpart) {
  const int s = blockIdx.x, j = threadIdx.x;
  const float* wp_base = w_proj + (size_t)s * EMBD * NCOL + j;
  float wreg[EMBD];
#pragma unroll
  for (int e = 0; e < EMBD; ++e) wreg[e] = wp_base[(size_t)e * NCOL];
  float bi = 0.f, be = 0.f;
#pragma unroll
  for (int e = 0; e < EMBD; ++e) {
    bi = fmaf(b_emb_imu[e], wreg[e], bi);
    be = fmaf(b_emb_emg[e], wreg[e], be);
  }
  bpart[(size_t)s * NCOL + j] = bi;
  bpart[((size_t)NEWL + s) * NCOL + j] = be;
  wcomb_body<CIMU, KSTI>(w_emb_imu, wreg, wpk_imu, s, j);
  wcomb_body<CEMG, KSTE>(w_emb_emg, wreg, wpk_emg, s, j);
}

// ---------- K1: fused ragged-interp + MFMA GEMM (+ bias-reduce tail block)
__global__ __launch_bounds__(256) void fused_kernel(
    const float* __restrict__ x_imu, const float* __restrict__ x_emg,
    const int* __restrict__ lens,
    const __bf16* __restrict__ wpk_imu, const __bf16* __restrict__ wpk_emg,
    const float* __restrict__ b_proj, const float* __restrict__ bpart,
    float* __restrict__ p_imu, float* __restrict__ p_emg,
    float* __restrict__ bias, int B, int T) {
  const int bid = blockIdx.x;
  const int span = B >> 4;  // blocks per chunk (mtiles*2)
  const int mts = B >> 5;   // 32-row m-tiles
  if (bid == (NCI + 1) * span) {  // bias tail block
    const int j = threadIdx.x;
#pragma unroll
    for (int m = 0; m < 2; ++m) {
      float acc = b_proj[j];
      for (int s = 0; s < NEWL; ++s) acc += bpart[((size_t)m * NEWL + s) * NCOL + j];
      bias[m * NCOL + j] = acc;
    }
    return;
  }

  __shared__ __bf16 lds[2][2][3][512];  // [buf][row-plane][ks][lane*8]

  const int tid = threadIdx.x;
  const int wv = tid >> 6, l = tid & 63;

  bool is_imu;
  int c, r;
  if (bid < NCI * span) { is_imu = true; c = bid / span; r = bid - c * span; }
  else { is_imu = false; c = 0; r = bid - NCI * span; }
  const int nh = r / mts, mt = r - nh * mts;

  const __bf16* Wp = is_imu ? wpk_imu : wpk_emg;
  const int KST = is_imu ? KSTI : KSTE;
  const int ks0 = is_imu ? c * 45 : 0;
  const int NG = is_imu ? NG_I : NG_E;
  float* P = is_imu ? (p_imu + (size_t)c * B * NCOL) : p_emg;

  const size_t PS = (size_t)KST * 512;  // B fragment-plane stride (bf16)
  const __bf16* bg = Wp + ((size_t)(nh * 8 + wv * 2) * KST + ks0) * 512 + l * 8;

  // gather thread mappings
  const int q = tid & 3, sl = (tid >> 2) & 1, bli = tid >> 3;  // imu: 4 thr/(b,s)
  const int ble = tid / 6, se = tid - ble * 6;                 // emg: 1 thr/(b,s), tid<192
  const bool act = is_imu || (tid < 192);
  const int b_g = mt * 32 + (is_imu ? bli : (act ? ble : 0));
  int lenv = 1;
  float scale = 0.f;
  if (act) { lenv = lens[b_g]; scale = (float)lenv * (1.0f / 150.0f); }
  const int prt_i = (l & ~3) | 2 | (q & 1);  // imu lerp partner lane

  float gr[2][32];   // gather reg slots (imu uses 24, emg 32)
  float wS[2];       // lerp weights per slot
  bf16x8_t bB[2][6]; // B fragment slots (2 planes x 3 ksteps)
  f32x4_t acc00 = {0.f, 0.f, 0.f, 0.f}, acc01 = acc00, acc10 = acc00, acc11 = acc00;

#define ISSUE_GI(g2, Pp) do {                                                   \
    const int s_ = c * SCH_I + (g2) * 2 + sl;                                   \
    float src_ = fmaxf(((float)s_ + 0.5f) * scale - 0.5f, 0.0f);                \
    int i0_ = min((int)src_, lenv - 1);                                         \
    int i1_ = min(i0_ + 1, lenv - 1);                                           \
    wS[Pp] = src_ - (float)i0_;                                                 \
    const float* p_ =                                                           \
        x_imu + ((size_t)b_g * T + ((q < 2) ? i0_ : i1_)) * CIMU + (q & 1) * 24;\
    _Pragma("unroll")                                                           \
    for (int t = 0; t < 6; ++t) {                                               \
      float4 v_ = *(const float4*)(p_ + t * 4);                                 \
      gr[Pp][t * 4 + 0] = v_.x; gr[Pp][t * 4 + 1] = v_.y;                       \
      gr[Pp][t * 4 + 2] = v_.z; gr[Pp][t * 4 + 3] = v_.w;                       \
    }                                                                           \
  } while (0)

#define LERP_WI(Pp, BUF) do {                                                   \
    const float wg_ = wS[Pp], om_ = 1.0f - wg_;                                 \
    _Pragma("unroll")                                                           \
    for (int t = 0; t < 6; ++t) {                                               \
      float a0_ = gr[Pp][t * 4 + 0], a1_ = gr[Pp][t * 4 + 1];                   \
      float a2_ = gr[Pp][t * 4 + 2], a3_ = gr[Pp][t * 4 + 3];                   \
      float p0_ = __shfl(a0_, prt_i), p1_ = __shfl(a1_, prt_i);                 \
      float p2_ = __shfl(a2_, prt_i), p3_ = __shfl(a3_, prt_i);                 \
      if (q < 2) {                                                              \
        bf16x4_t o_;                                                            \
        o_[0] = (__bf16)(a0_ * om_ + p0_ * wg_);                                \
        o_[1] = (__bf16)(a1_ * om_ + p1_ * wg_);                                \
        o_[2] = (__bf16)(a2_ * om_ + p2_ * wg_);                                \
        o_[3] = (__bf16)(a3_ * om_ + p3_ * wg_);                                \
        const int kq_ = sl * 6 + q * 3 + (t >> 1);                              \
        *(bf16x4_t*)(&lds[BUF][bli >> 4][kq_ >> 2]                              \
                         [((kq_ & 3) * 16 + (bli & 15)) * 8 + (t & 1) * 4]) = o_;\
      }                                                                         \
    }                                                                           \
  } while (0)

#define ISSUE_GE(g2, Pp) do { if (act) {                                        \
    const int s_ = (g2) * 6 + se;                                               \
    float src_ = fmaxf(((float)s_ + 0.5f) * scale - 0.5f, 0.0f);                \
    int i0_ = min((int)src_, lenv - 1);                                         \
    int i1_ = min(i0_ + 1, lenv - 1);                                           \
    wS[Pp] = src_ - (float)i0_;                                                 \
    const float* p0_ = x_emg + ((size_t)b_g * T + i0_) * CEMG;                  \
    const float* p1_ = x_emg + ((size_t)b_g * T + i1_) * CEMG;                  \
    _Pragma("unroll")                                                           \
    for (int t = 0; t < 4; ++t) {                                               \
      float4 v_ = *(const float4*)(p0_ + t * 4);                                \
      gr[Pp][t * 4 + 0] = v_.x; gr[Pp][t * 4 + 1] = v_.y;                       \
      gr[Pp][t * 4 + 2] = v_.z; gr[Pp][t * 4 + 3] = v_.w;                       \
      float4 u_ = *(const float4*)(p1_ + t * 4);                                \
      gr[Pp][16 + t * 4 + 0] = u_.x; gr[Pp][16 + t * 4 + 1] = u_.y;             \
      gr[Pp][16 + t * 4 + 2] = u_.z; gr[Pp][16 + t * 4 + 3] = u_.w;             \
    }                                                                           \
  } } while (0)

#define LERP_WE(Pp, BUF) do { if (act) {                                        \
    const float wg_ = wS[Pp], om_ = 1.0f - wg_;                                 \
    _Pragma("unroll")                                                           \
    for (int t2 = 0; t2 < 2; ++t2) {                                            \
      bf16x8_t o_;                                                              \
      _Pragma("unroll")                                                         \
      for (int u = 0; u < 8; ++u)                                               \
        o_[u] = (__bf16)(gr[Pp][t2 * 8 + u] * om_ +                             \
                         gr[Pp][16 + t2 * 8 + u] * wg_);                        \
      const int kq_ = se * 2 + t2;                                              \
      *(bf16x8_t*)(&lds[BUF][ble >> 4][kq_ >> 2]                                \
                       [((kq_ & 3) * 16 + (ble & 15)) * 8]) = o_;               \
    }                                                                           \
  } } while (0)

#define ISSUE_B(g1, Ss) do {                                                    \
    const __bf16* pb_ = bg + (size_t)((g1) * 3) * 512;                          \
    _Pragma("unroll")                                                           \
    for (int ks = 0; ks < 3; ++ks) {                                            \
      bB[Ss][ks * 2 + 0] = *(const bf16x8_t*)(pb_ + (size_t)ks * 512);          \
      bB[Ss][ks * 2 + 1] = *(const bf16x8_t*)(pb_ + PS + (size_t)ks * 512);     \
    }                                                                           \
  } while (0)

#define COMPUTE(Pp) do {                                                        \
    _Pragma("unroll")                                                           \
    for (int ks = 0; ks < 3; ++ks) {                                            \
      bf16x8_t a0_ = *(const bf16x8_t*)(&lds[Pp][0][ks][l * 8]);                \
      bf16x8_t a1_ = *(const bf16x8_t*)(&lds[Pp][1][ks][l * 8]);                \
      acc00 = mfma16(a0_, bB[Pp][ks * 2 + 0], acc00);                           \
      acc01 = mfma16(a0_, bB[Pp][ks * 2 + 1], acc01);                           \
      acc10 = mfma16(a1_, bB[Pp][ks * 2 + 0], acc10);                           \
      acc11 = mfma16(a1_, bB[Pp][ks * 2 + 1], acc11);                           \
    }                                                                           \
  } while (0)

  // prologue: 2 gather sets + 1 B set in flight, group 0 staged
  if (is_imu) { ISSUE_GI(0, 0); ISSUE_GI(1, 1); }
  else        { ISSUE_GE(0, 0); ISSUE_GE(1, 1); }
  ISSUE_B(0, 0);
  if (is_imu) LERP_WI(0, 0); else LERP_WE(0, 0);
  BARB();

  for (int gp = 0; gp < (NG + 1) / 2; ++gp) {
    const int g = gp * 2;
    {
      if (g + 2 < NG) { if (is_imu) ISSUE_GI(g + 2, 0); else ISSUE_GE(g + 2, 0); }
      if (g + 1 < NG) ISSUE_B(g + 1, 1);
      COMPUTE(0);
      if (g + 1 < NG) { if (is_imu) LERP_WI(1, 1); else LERP_WE(1, 1); }
      BARB();
    }
    if (g + 1 < NG) {
      if (g + 3 < NG) { if (is_imu) ISSUE_GI(g + 3, 1); else ISSUE_GE(g + 3, 1); }
      if (g + 2 < NG) ISSUE_B(g + 2, 0);
      COMPUTE(1);
      if (g + 2 < NG) { if (is_imu) LERP_WI(0, 0); else LERP_WE(0, 0); }
      BARB();
    }
  }

  // epilogue: C/D col = lane&15, row = (lane>>4)*4 + reg
  const int lh = l >> 4, lr = l & 15;
  float* Pb = P + (size_t)(mt * 32 + lh * 4) * NCOL + nh * 128 + wv * 32 + lr;
#pragma unroll
  for (int jj = 0; jj < 4; ++jj) {
    Pb[(size_t)jj * NCOL] = acc00[jj];
    Pb[(size_t)jj * NCOL + 16] = acc01[jj];
    Pb[(size_t)(16 + jj) * NCOL] = acc10[jj];
    Pb[(size_t)(16 + jj) * NCOL + 16] = acc11[jj];
  }
#undef ISSUE_GI
#undef LERP_WI
#undef ISSUE_GE
#undef LERP_WE
#undef ISSUE_B
#undef COMPUTE
}

// ---------- K2: sum split-K partials + bias -> d_out
__global__ __launch_bounds__(256) void combine_kernel(
    const float* __restrict__ bias, const float* __restrict__ p_imu,
    const float* __restrict__ p_emg, float* __restrict__ out, int B) {
  const int b = blockIdx.x, m = blockIdx.y, j = threadIdx.x;
  const size_t n = (size_t)B * NCOL;
  const size_t o = (size_t)b * NCOL + j;
  if (m == 0) {
    float v = bias[j];
#pragma unroll
    for (int c = 0; c < NCI; ++c) v += p_imu[c * n + o];
    out[o] = v;
  } else {
    out[n + o] = bias[NCOL + j] + p_emg[o];
  }
}

extern "C" void kernel_launch(void* const* d_in, const int* in_sizes, int n_in,
                              void* d_out, int out_size, void* d_ws, size_t ws_size,
                              hipStream_t stream) {
  const float* x_imu     = (const float*)d_in[0];
  const float* x_emg     = (const float*)d_in[1];
  const int*   lens      = (const int*)d_in[2];
  const float* w_emb_imu = (const float*)d_in[3];
  const float* b_emb_imu = (const float*)d_in[4];
  const float* w_emb_emg = (const float*)d_in[5];
  const float* b_emb_emg = (const float*)d_in[6];
  const float* w_proj    = (const float*)d_in[7];
  const float* b_proj    = (const float*)d_in[8];
  float* out = (float*)d_out;

  const int B = in_sizes[2];
  const int T = in_sizes[0] / (B * CIMU);

  char* ws = (char*)d_ws;
  __bf16* wpk_imu = (__bf16*)ws;  ws += (size_t)NCOL * KIMU * 2;
  __bf16* wpk_emg = (__bf16*)ws;  ws += (size_t)NCOL * KEMG * 2;
  float*  bias    = (float*)ws;   ws += 2 * NCOL * 4;
  float*  bpart   = (float*)ws;   ws += (size_t)2 * NEWL * NCOL * 4;
  float*  p_imu   = (float*)ws;   ws += (size_t)NCI * B * NCOL * 4;
  float*  p_emg   = (float*)ws;   ws += (size_t)B * NCOL * 4;

  wcomb_kernel<<<NEWL, 256, 0, stream>>>(w_emb_imu, w_emb_emg, b_emb_imu,
                                         b_emb_emg, w_proj, wpk_imu, wpk_emg,
                                         bpart);
  const int span = B >> 4;                    // 128
  const int nblk = (NCI + 1) * span + 1;      // 769
  fused_kernel<<<nblk, 256, 0, stream>>>(x_imu, x_emg, lens, wpk_imu, wpk_emg,
                                         b_proj, bpart, p_imu, p_emg, bias, B, T);
  combine_kernel<<<dim3(B, 2), 256, 0, stream>>>(bias, p_imu, p_emg, out, B);
}

// Round 10
// 94.065 us; speedup vs baseline: 1.2075x; 1.1698x over previous
//
#include <hip/hip_runtime.h>

#define NEWL 150
#define EMBD 64
#define NCOL 256
#define CIMU 48
#define CEMG 16

#define KIMU (NEWL * CIMU)  // 7200
#define KEMG (NEWL * CEMG)  // 2400
#define KSTI 225            // total k-steps (32-wide) imu
#define KSTE 75             // total k-steps emg
#define NCI 5               // imu s-chunks (30 s each -> 45 ksteps)
#define SCH_I 30
#define NG_I 15             // groups per imu chunk (2 s -> 3 ksteps each)
#define NG_E 25             // groups per emg chunk (6 s -> 3 ksteps each)

typedef __bf16 bf16x8_t __attribute__((ext_vector_type(8)));
typedef __bf16 bf16x4_t __attribute__((ext_vector_type(4)));
typedef float f32x4_t __attribute__((ext_vector_type(4)));

__device__ __forceinline__ f32x4_t mfma16(bf16x8_t a, bf16x8_t b, f32x4_t c) {
  return __builtin_amdgcn_mfma_f32_16x16x32_bf16(a, b, c, 0, 0, 0);
}

// quad_perm:[2,3,2,3] — lane q in each 4-lane quad reads quad element 2+(q&1).
// Replaces ds_bpermute-based __shfl for the imu lerp partner: pure VALU (DPP),
// no LDS-pipe traffic.  ctrl = 2 | 3<<2 | 2<<4 | 3<<6 = 0xEE.
__device__ __forceinline__ float dpp2323(float x) {
  return __int_as_float(
      __builtin_amdgcn_mov_dpp(__float_as_int(x), 0xEE, 0xF, 0xF, false));
}

// ---------- K0: combined weights packed in MFMA B-fragment order + bias partials.
// W_pack[cb][ks][lane=h*16+(col&15)][u]  where k = ks*32 + h*8 + u
template <int C, int KST>
__device__ void wcomb_body(const float* __restrict__ wemb,
                           const float* __restrict__ wreg_src,
                           __bf16* __restrict__ wpk, int s, int j) {
  float wreg[EMBD];
#pragma unroll
  for (int e = 0; e < EMBD; ++e) wreg[e] = wreg_src[(size_t)e * NCOL];
  const int cb = j >> 4, lr = j & 15;
#pragma unroll
  for (int q = 0; q < C / 8; ++q) {
    const int kq = (s * C) / 8 + q;
    const int ks = kq >> 2, h = kq & 3;
    bf16x8_t tv;
#pragma unroll
    for (int u = 0; u < 8; ++u) {
      const float* we = wemb + (q * 8 + u) * EMBD;
      float acc = 0.f;
#pragma unroll
      for (int e = 0; e < EMBD; ++e) acc = fmaf(we[e], wreg[e], acc);
      tv[u] = (__bf16)acc;
    }
    *(bf16x8_t*)(wpk + (((size_t)cb * KST + ks) * 64 + h * 16 + lr) * 8) = tv;
  }
}

__global__ __launch_bounds__(256) void wcomb_kernel(
    const float* __restrict__ w_emb_imu, const float* __restrict__ w_emb_emg,
    const float* __restrict__ b_emb_imu, const float* __restrict__ b_emb_emg,
    const float* __restrict__ w_proj,
    __bf16* __restrict__ wpk_imu, __bf16* __restrict__ wpk_emg,
    float* __restrict__ bpart) {
  const int s = blockIdx.x;   // 0..149
  const int m = blockIdx.y;   // 0 = imu, 1 = emg
  const int j = threadIdx.x;  // output column 0..255
  const float* wp_base = w_proj + (size_t)s * EMBD * NCOL + j;
  const float* be = (m == 0) ? b_emb_imu : b_emb_emg;
  float bacc = 0.f;
#pragma unroll
  for (int e = 0; e < EMBD; ++e) bacc = fmaf(be[e], wp_base[(size_t)e * NCOL], bacc);
  bpart[((size_t)m * NEWL + s) * NCOL + j] = bacc;
  if (m == 0)
    wcomb_body<CIMU, KSTI>(w_emb_imu, wp_base, wpk_imu, s, j);
  else
    wcomb_body<CEMG, KSTE>(w_emb_emg, wp_base, wpk_emg, s, j);
}

// ---------- K1: fused ragged-interp + MFMA GEMM (+ bias-reduce tail block)
__global__ __launch_bounds__(256) void fused_kernel(
    const float* __restrict__ x_imu, const float* __restrict__ x_emg,
    const int* __restrict__ lens,
    const __bf16* __restrict__ wpk_imu, const __bf16* __restrict__ wpk_emg,
    const float* __restrict__ b_proj, const float* __restrict__ bpart,
    float* __restrict__ p_imu, float* __restrict__ p_emg,
    float* __restrict__ bias, int B, int T) {
  const int bid = blockIdx.x;
  const int span = B >> 4;  // blocks per chunk (mtiles*2)
  const int mts = B >> 5;   // 32-row m-tiles
  if (bid == (NCI + 1) * span) {  // bias tail block
    const int j = threadIdx.x;
#pragma unroll
    for (int m = 0; m < 2; ++m) {
      float acc = b_proj[j];
      for (int s = 0; s < NEWL; ++s) acc += bpart[((size_t)m * NEWL + s) * NCOL + j];
      bias[m * NCOL + j] = acc;
    }
    return;
  }

  __shared__ __bf16 lds[2][2][3][512];  // [buf][row-plane][ks][lane*8]

  const int tid = threadIdx.x;
  const int wv = tid >> 6, l = tid & 63;

  bool is_imu;
  int c, r;
  if (bid < NCI * span) { is_imu = true; c = bid / span; r = bid - c * span; }
  else { is_imu = false; c = 0; r = bid - NCI * span; }
  const int nh = r / mts, mt = r - nh * mts;

  const __bf16* Wp = is_imu ? wpk_imu : wpk_emg;
  const int KST = is_imu ? KSTI : KSTE;
  const int ks0 = is_imu ? c * 45 : 0;
  const int NG = is_imu ? NG_I : NG_E;
  float* P = is_imu ? (p_imu + (size_t)c * B * NCOL) : p_emg;

  const size_t PS = (size_t)KST * 512;  // B fragment-plane stride (bf16)
  const __bf16* bg = Wp + ((size_t)(nh * 8 + wv * 2) * KST + ks0) * 512 + l * 8;

  // gather thread mappings
  const int q = tid & 3, sl = (tid >> 2) & 1, bli = tid >> 3;  // imu: 4 thr/(b,s)
  const int ble = tid / 6, se = tid - ble * 6;                 // emg: 1 thr/(b,s), tid<192
  const bool act = is_imu || (tid < 192);
  const int b_g = mt * 32 + (is_imu ? bli : (act ? ble : 0));
  int lenv = 1;
  float scale = 0.f;
  if (act) { lenv = lens[b_g]; scale = (float)lenv * (1.0f / 150.0f); }

  float gr[2][32];   // gather reg slots (imu uses 24, emg 32)
  float wS[2];       // lerp weights per slot
  bf16x8_t bB[2][6]; // B fragment slots (2 planes x 3 ksteps)
  f32x4_t acc00 = {0.f, 0.f, 0.f, 0.f}, acc01 = acc00, acc10 = acc00, acc11 = acc00;

#define ISSUE_GI(g2, Pp) do {                                                   \
    const int s_ = c * SCH_I + (g2) * 2 + sl;                                   \
    float src_ = fmaxf(((float)s_ + 0.5f) * scale - 0.5f, 0.0f);                \
    int i0_ = min((int)src_, lenv - 1);                                         \
    int i1_ = min(i0_ + 1, lenv - 1);                                           \
    wS[Pp] = src_ - (float)i0_;                                                 \
    const float* p_ =                                                           \
        x_imu + ((size_t)b_g * T + ((q < 2) ? i0_ : i1_)) * CIMU + (q & 1) * 24;\
    _Pragma("unroll")                                                           \
    for (int t = 0; t < 6; ++t) {                                               \
      float4 v_ = *(const float4*)(p_ + t * 4);                                 \
      gr[Pp][t * 4 + 0] = v_.x; gr[Pp][t * 4 + 1] = v_.y;                       \
      gr[Pp][t * 4 + 2] = v_.z; gr[Pp][t * 4 + 3] = v_.w;                       \
    }                                                                           \
  } while (0)

#define LERP_WI(Pp, BUF) do {                                                   \
    const float wg_ = wS[Pp], om_ = 1.0f - wg_;                                 \
    _Pragma("unroll")                                                           \
    for (int t = 0; t < 6; ++t) {                                               \
      float a0_ = gr[Pp][t * 4 + 0], a1_ = gr[Pp][t * 4 + 1];                   \
      float a2_ = gr[Pp][t * 4 + 2], a3_ = gr[Pp][t * 4 + 3];                   \
      float p0_ = dpp2323(a0_), p1_ = dpp2323(a1_);                             \
      float p2_ = dpp2323(a2_), p3_ = dpp2323(a3_);                             \
      if (q < 2) {                                                              \
        bf16x4_t o_;                                                            \
        o_[0] = (__bf16)(a0_ * om_ + p0_ * wg_);                                \
        o_[1] = (__bf16)(a1_ * om_ + p1_ * wg_);                                \
        o_[2] = (__bf16)(a2_ * om_ + p2_ * wg_);                                \
        o_[3] = (__bf16)(a3_ * om_ + p3_ * wg_);                                \
        const int kq_ = sl * 6 + q * 3 + (t >> 1);                              \
        *(bf16x4_t*)(&lds[BUF][bli >> 4][kq_ >> 2]                              \
                         [((kq_ & 3) * 16 + (bli & 15)) * 8 + (t & 1) * 4]) = o_;\
      }                                                                         \
    }                                                                           \
  } while (0)

#define ISSUE_GE(g2, Pp) do { if (act) {                                        \
    const int s_ = (g2) * 6 + se;                                               \
    float src_ = fmaxf(((float)s_ + 0.5f) * scale - 0.5f, 0.0f);                \
    int i0_ = min((int)src_, lenv - 1);                                         \
    int i1_ = min(i0_ + 1, lenv - 1);                                           \
    wS[Pp] = src_ - (float)i0_;                                                 \
    const float* p0_ = x_emg + ((size_t)b_g * T + i0_) * CEMG;                  \
    const float* p1_ = x_emg + ((size_t)b_g * T + i1_) * CEMG;                  \
    _Pragma("unroll")                                                           \
    for (int t = 0; t < 4; ++t) {                                               \
      float4 v_ = *(const float4*)(p0_ + t * 4);                                \
      gr[Pp][t * 4 + 0] = v_.x; gr[Pp][t * 4 + 1] = v_.y;                       \
      gr[Pp][t * 4 + 2] = v_.z; gr[Pp][t * 4 + 3] = v_.w;                       \
      float4 u_ = *(const float4*)(p1_ + t * 4);                                \
      gr[Pp][16 + t * 4 + 0] = u_.x; gr[Pp][16 + t * 4 + 1] = u_.y;             \
      gr[Pp][16 + t * 4 + 2] = u_.z; gr[Pp][16 + t * 4 + 3] = u_.w;             \
    }                                                                           \
  } } while (0)

#define LERP_WE(Pp, BUF) do { if (act) {                                        \
    const float wg_ = wS[Pp], om_ = 1.0f - wg_;                                 \
    _Pragma("unroll")                                                           \
    for (int t2 = 0; t2 < 2; ++t2) {                                            \
      bf16x8_t o_;                                                              \
      _Pragma("unroll")                                                         \
      for (int u = 0; u < 8; ++u)                                               \
        o_[u] = (__bf16)(gr[Pp][t2 * 8 + u] * om_ +                             \
                         gr[Pp][16 + t2 * 8 + u] * wg_);                        \
      const int kq_ = se * 2 + t2;                                              \
      *(bf16x8_t*)(&lds[BUF][ble >> 4][kq_ >> 2]                                \
                       [((kq_ & 3) * 16 + (ble & 15)) * 8]) = o_;               \
    }                                                                           \
  } } while (0)

#define ISSUE_B(g1, Ss) do {                                                    \
    const __bf16* pb_ = bg + (size_t)((g1) * 3) * 512;                          \
    _Pragma("unroll")                                                           \
    for (int ks = 0; ks < 3; ++ks) {                                            \
      bB[Ss][ks * 2 + 0] = *(const bf16x8_t*)(pb_ + (size_t)ks * 512);          \
      bB[Ss][ks * 2 + 1] = *(const bf16x8_t*)(pb_ + PS + (size_t)ks * 512);     \
    }                                                                           \
  } while (0)

#define COMPUTE(Pp) do {                                                        \
    _Pragma("unroll")                                                           \
    for (int ks = 0; ks < 3; ++ks) {                                            \
      bf16x8_t a0_ = *(const bf16x8_t*)(&lds[Pp][0][ks][l * 8]);                \
      bf16x8_t a1_ = *(const bf16x8_t*)(&lds[Pp][1][ks][l * 8]);                \
      acc00 = mfma16(a0_, bB[Pp][ks * 2 + 0], acc00);                           \
      acc01 = mfma16(a0_, bB[Pp][ks * 2 + 1], acc01);                           \
      acc10 = mfma16(a1_, bB[Pp][ks * 2 + 0], acc10);                           \
      acc11 = mfma16(a1_, bB[Pp][ks * 2 + 1], acc11);                           \
    }                                                                           \
  } while (0)

  // prologue: 2 gather sets + 1 B set in flight, group 0 staged
  if (is_imu) { ISSUE_GI(0, 0); ISSUE_GI(1, 1); }
  else        { ISSUE_GE(0, 0); ISSUE_GE(1, 1); }
  ISSUE_B(0, 0);
  if (is_imu) LERP_WI(0, 0); else LERP_WE(0, 0);
  __syncthreads();

  for (int gp = 0; gp < (NG + 1) / 2; ++gp) {
    const int g = gp * 2;
    {
      if (g + 2 < NG) { if (is_imu) ISSUE_GI(g + 2, 0); else ISSUE_GE(g + 2, 0); }
      if (g + 1 < NG) ISSUE_B(g + 1, 1);
      COMPUTE(0);
      if (g + 1 < NG) { if (is_imu) LERP_WI(1, 1); else LERP_WE(1, 1); }
      __syncthreads();
    }
    if (g + 1 < NG) {
      if (g + 3 < NG) { if (is_imu) ISSUE_GI(g + 3, 1); else ISSUE_GE(g + 3, 1); }
      if (g + 2 < NG) ISSUE_B(g + 2, 0);
      COMPUTE(1);
      if (g + 2 < NG) { if (is_imu) LERP_WI(0, 0); else LERP_WE(0, 0); }
      __syncthreads();
    }
  }

  // epilogue: C/D col = lane&15, row = (lane>>4)*4 + reg
  const int lh = l >> 4, lr = l & 15;
  float* Pb = P + (size_t)(mt * 32 + lh * 4) * NCOL + nh * 128 + wv * 32 + lr;
#pragma unroll
  for (int jj = 0; jj < 4; ++jj) {
    Pb[(size_t)jj * NCOL] = acc00[jj];
    Pb[(size_t)jj * NCOL + 16] = acc01[jj];
    Pb[(size_t)(16 + jj) * NCOL] = acc10[jj];
    Pb[(size_t)(16 + jj) * NCOL + 16] = acc11[jj];
  }
#undef ISSUE_GI
#undef LERP_WI
#undef ISSUE_GE
#undef LERP_WE
#undef ISSUE_B
#undef COMPUTE
}

// ---------- K2: sum split-K partials + bias -> d_out
__global__ __launch_bounds__(256) void combine_kernel(
    const float* __restrict__ bias, const float* __restrict__ p_imu,
    const float* __restrict__ p_emg, float* __restrict__ out, int B) {
  const int b = blockIdx.x, m = blockIdx.y, j = threadIdx.x;
  const size_t n = (size_t)B * NCOL;
  const size_t o = (size_t)b * NCOL + j;
  if (m == 0) {
    float v = bias[j];
#pragma unroll
    for (int c = 0; c < NCI; ++c) v += p_imu[c * n + o];
    out[o] = v;
  } else {
    out[n + o] = bias[NCOL + j] + p_emg[o];
  }
}

extern "C" void kernel_launch(void* const* d_in, const int* in_sizes, int n_in,
                              void* d_out, int out_size, void* d_ws, size_t ws_size,
                              hipStream_t stream) {
  const float* x_imu     = (const float*)d_in[0];
  const float* x_emg     = (const float*)d_in[1];
  const int*   lens      = (const int*)d_in[2];
  const float* w_emb_imu = (const float*)d_in[3];
  const float* b_emb_imu = (const float*)d_in[4];
  const float* w_emb_emg = (const float*)d_in[5];
  const float* b_emb_emg = (const float*)d_in[6];
  const float* w_proj    = (const float*)d_in[7];
  const float* b_proj    = (const float*)d_in[8];
  float* out = (float*)d_out;

  const int B = in_sizes[2];
  const int T = in_sizes[0] / (B * CIMU);

  char* ws = (char*)d_ws;
  __bf16* wpk_imu = (__bf16*)ws;  ws += (size_t)NCOL * KIMU * 2;
  __bf16* wpk_emg = (__bf16*)ws;  ws += (size_t)NCOL * KEMG * 2;
  float*  bias    = (float*)ws;   ws += 2 * NCOL * 4;
  float*  bpart   = (float*)ws;   ws += (size_t)2 * NEWL * NCOL * 4;
  float*  p_imu   = (float*)ws;   ws += (size_t)NCI * B * NCOL * 4;
  float*  p_emg   = (float*)ws;   ws += (size_t)B * NCOL * 4;

  wcomb_kernel<<<dim3(NEWL, 2), 256, 0, stream>>>(
      w_emb_imu, w_emb_emg, b_emb_imu, b_emb_emg, w_proj, wpk_imu, wpk_emg, bpart);
  const int span = B >> 4;                    // 128
  const int nblk = (NCI + 1) * span + 1;      // 769
  fused_kernel<<<nblk, 256, 0, stream>>>(x_imu, x_emg, lens, wpk_imu, wpk_emg,
                                         b_proj, bpart, p_imu, p_emg, bias, B, T);
  combine_kernel<<<dim3(B, 2), 256, 0, stream>>>(bias, p_imu, p_emg, out, B);
}

// Round 11
// 84.143 us; speedup vs baseline: 1.3499x; 1.1179x over previous
//
#include <hip/hip_runtime.h>

#define NEWL 150
#define EMBD 64
#define NCOL 256
#define CIMU 48
#define CEMG 16

#define KIMU (NEWL * CIMU)  // 7200
#define KEMG (NEWL * CEMG)  // 2400
#define KSTI 225            // total k-steps (32-wide) imu
#define KSTE 75             // total k-steps emg
#define NCI 4               // imu s-chunks (19/19/19/18 groups)
#define NCE 2               // emg s-chunks (13/12 groups)

typedef __bf16 bf16x8_t __attribute__((ext_vector_type(8)));
typedef __bf16 bf16x4_t __attribute__((ext_vector_type(4)));
typedef float f32x4_t __attribute__((ext_vector_type(4)));

__device__ __forceinline__ f32x4_t mfma16(bf16x8_t a, bf16x8_t b, f32x4_t c) {
  return __builtin_amdgcn_mfma_f32_16x16x32_bf16(a, b, c, 0, 0, 0);
}

// ---------- K0: combined weights packed in MFMA B-fragment order + bias partials.
// W_pack[cb][ks][lane=h*16+(col&15)][u]  where k = ks*32 + h*8 + u
template <int C, int KST>
__device__ void wcomb_body(const float* __restrict__ wemb,
                           const float* __restrict__ wreg_src,
                           __bf16* __restrict__ wpk, int s, int j) {
  float wreg[EMBD];
#pragma unroll
  for (int e = 0; e < EMBD; ++e) wreg[e] = wreg_src[(size_t)e * NCOL];
  const int cb = j >> 4, lr = j & 15;
#pragma unroll
  for (int q = 0; q < C / 8; ++q) {
    const int kq = (s * C) / 8 + q;
    const int ks = kq >> 2, h = kq & 3;
    bf16x8_t tv;
#pragma unroll
    for (int u = 0; u < 8; ++u) {
      const float* we = wemb + (q * 8 + u) * EMBD;
      float acc = 0.f;
#pragma unroll
      for (int e = 0; e < EMBD; ++e) acc = fmaf(we[e], wreg[e], acc);
      tv[u] = (__bf16)acc;
    }
    *(bf16x8_t*)(wpk + (((size_t)cb * KST + ks) * 64 + h * 16 + lr) * 8) = tv;
  }
}

__global__ __launch_bounds__(256) void wcomb_kernel(
    const float* __restrict__ w_emb_imu, const float* __restrict__ w_emb_emg,
    const float* __restrict__ b_emb_imu, const float* __restrict__ b_emb_emg,
    const float* __restrict__ w_proj,
    __bf16* __restrict__ wpk_imu, __bf16* __restrict__ wpk_emg,
    float* __restrict__ bpart) {
  const int s = blockIdx.x;   // 0..149
  const int m = blockIdx.y;   // 0 = imu, 1 = emg
  const int j = threadIdx.x;  // output column 0..255
  const float* wp_base = w_proj + (size_t)s * EMBD * NCOL + j;
  const float* be = (m == 0) ? b_emb_imu : b_emb_emg;
  float bacc = 0.f;
#pragma unroll
  for (int e = 0; e < EMBD; ++e) bacc = fmaf(be[e], wp_base[(size_t)e * NCOL], bacc);
  bpart[((size_t)m * NEWL + s) * NCOL + j] = bacc;
  if (m == 0)
    wcomb_body<CIMU, KSTI>(w_emb_imu, wp_base, wpk_imu, s, j);
  else
    wcomb_body<CEMG, KSTE>(w_emb_emg, wp_base, wpk_emg, s, j);
}

// ---------- K1: fused ragged-interp + MFMA GEMM (+ bias-reduce tail block)
__global__ __launch_bounds__(256) void fused_kernel(
    const float* __restrict__ x_imu, const float* __restrict__ x_emg,
    const int* __restrict__ lens,
    const __bf16* __restrict__ wpk_imu, const __bf16* __restrict__ wpk_emg,
    const float* __restrict__ b_proj, const float* __restrict__ bpart,
    float* __restrict__ p_imu, float* __restrict__ p_emg,
    float* __restrict__ bias, int B, int T) {
  const int bid = blockIdx.x;
  const int span = B >> 4;  // blocks per chunk (mtiles*2)
  const int mts = B >> 5;   // 32-row m-tiles
  if (bid == (NCE + NCI) * span) {  // bias tail block
    const int j = threadIdx.x;
#pragma unroll
    for (int m = 0; m < 2; ++m) {
      float acc = b_proj[j];
      for (int s = 0; s < NEWL; ++s) acc += bpart[((size_t)m * NEWL + s) * NCOL + j];
      bias[m * NCOL + j] = acc;
    }
    return;
  }

  __shared__ __bf16 lds[2][2][3][512];  // [buf][row-plane][ks][lane*8]

  const int tid = threadIdx.x;
  const int wv = tid >> 6, l = tid & 63;

  // emg chunks first (bids 0..2*span), then imu (order irrelevant; all resident)
  const int cs = bid / span;
  const int r = bid - cs * span;
  const bool is_imu = cs >= NCE;
  const int c = is_imu ? cs - NCE : cs;
  const int nh = r / mts, mt = r - nh * mts;

  // chunk geometry (group = 3 ksteps; imu: 2 s/group, emg: 6 s/group)
  int g0, NG;
  if (is_imu) { g0 = 19 * c; NG = (c < 3) ? 19 : 18; }
  else        { g0 = 13 * c; NG = c ? 12 : 13; }
  const int ks0 = 3 * g0;
  const int sb = is_imu ? 2 * g0 : 6 * g0;

  const __bf16* Wp = is_imu ? wpk_imu : wpk_emg;
  const int KST = is_imu ? KSTI : KSTE;
  float* P = is_imu ? (p_imu + (size_t)c * B * NCOL) : (p_emg + (size_t)c * B * NCOL);

  const size_t PS = (size_t)KST * 512;  // B fragment-plane stride (bf16)
  const __bf16* bg = Wp + ((size_t)(nh * 8 + wv * 2) * KST + ks0) * 512 + l * 8;

  // gather thread mappings
  const int q = tid & 3, sl = (tid >> 2) & 1, bli = tid >> 3;  // imu: 4 thr/(b,s)
  const int ble = tid / 6, se = tid - ble * 6;                 // emg: 1 thr/(b,s), tid<192
  const bool act = is_imu || (tid < 192);
  const int b_g = mt * 32 + (is_imu ? bli : (act ? ble : 0));
  int lenv = 1;
  float scale = 0.f;
  if (act) { lenv = lens[b_g]; scale = (float)lenv * (1.0f / 150.0f); }

  float gr[2][32];   // gather reg slots (imu uses 24, emg 32)
  float wS[2];       // lerp weights per slot
  bf16x8_t bB[2][6]; // B fragment slots (2 planes x 3 ksteps)
  f32x4_t acc00 = {0.f, 0.f, 0.f, 0.f}, acc01 = acc00, acc10 = acc00, acc11 = acc00;

// imu gather, quad-contiguous: lane q reads row bytes [t*64 + q*16) of BOTH
// rows -> 16 lines per wave-instruction (was 64) and lerp partner is IN-LANE.
#define ISSUE_GI(g2, Pp) do {                                                   \
    const int s_ = sb + (g2) * 2 + sl;                                          \
    float src_ = fmaxf(((float)s_ + 0.5f) * scale - 0.5f, 0.0f);                \
    int i0_ = min((int)src_, lenv - 1);                                         \
    int i1_ = min(i0_ + 1, lenv - 1);                                           \
    wS[Pp] = src_ - (float)i0_;                                                 \
    const float* r0_ = x_imu + ((size_t)b_g * T + i0_) * CIMU + q * 4;          \
    const float* r1_ = x_imu + ((size_t)b_g * T + i1_) * CIMU + q * 4;          \
    _Pragma("unroll")                                                           \
    for (int t = 0; t < 3; ++t) {                                               \
      float4 v_ = *(const float4*)(r0_ + t * 16);                               \
      gr[Pp][t * 4 + 0] = v_.x; gr[Pp][t * 4 + 1] = v_.y;                       \
      gr[Pp][t * 4 + 2] = v_.z; gr[Pp][t * 4 + 3] = v_.w;                       \
      float4 u_ = *(const float4*)(r1_ + t * 16);                               \
      gr[Pp][12 + t * 4 + 0] = u_.x; gr[Pp][12 + t * 4 + 1] = u_.y;             \
      gr[Pp][12 + t * 4 + 2] = u_.z; gr[Pp][12 + t * 4 + 3] = u_.w;             \
    }                                                                           \
  } while (0)

// in-lane lerp; all 4 quad threads write distinct bf16x4 pieces.
// piece (t,q) = channels t*16+q*4.. -> k'' = sl*48 + t*16 + q*4
#define LERP_WI(Pp, BUF) do {                                                   \
    const float wg_ = wS[Pp], om_ = 1.0f - wg_;                                 \
    _Pragma("unroll")                                                           \
    for (int t = 0; t < 3; ++t) {                                               \
      bf16x4_t o_;                                                              \
      _Pragma("unroll")                                                         \
      for (int u = 0; u < 4; ++u)                                               \
        o_[u] = (__bf16)(gr[Pp][t * 4 + u] * om_ +                              \
                         gr[Pp][12 + t * 4 + u] * wg_);                         \
      const int kq_ = sl * 6 + t * 2 + (q >> 1);                                \
      *(bf16x4_t*)(&lds[BUF][bli >> 4][kq_ >> 2]                                \
                       [((kq_ & 3) * 16 + (bli & 15)) * 8 + (q & 1) * 4]) = o_; \
    }                                                                           \
  } while (0)

#define ISSUE_GE(g2, Pp) do { if (act) {                                        \
    const int s_ = sb + (g2) * 6 + se;                                          \
    float src_ = fmaxf(((float)s_ + 0.5f) * scale - 0.5f, 0.0f);                \
    int i0_ = min((int)src_, lenv - 1);                                         \
    int i1_ = min(i0_ + 1, lenv - 1);                                           \
    wS[Pp] = src_ - (float)i0_;                                                 \
    const float* p0_ = x_emg + ((size_t)b_g * T + i0_) * CEMG;                  \
    const float* p1_ = x_emg + ((size_t)b_g * T + i1_) * CEMG;                  \
    _Pragma("unroll")                                                           \
    for (int t = 0; t < 4; ++t) {                                               \
      float4 v_ = *(const float4*)(p0_ + t * 4);                                \
      gr[Pp][t * 4 + 0] = v_.x; gr[Pp][t * 4 + 1] = v_.y;                       \
      gr[Pp][t * 4 + 2] = v_.z; gr[Pp][t * 4 + 3] = v_.w;                       \
      float4 u_ = *(const float4*)(p1_ + t * 4);                                \
      gr[Pp][16 + t * 4 + 0] = u_.x; gr[Pp][16 + t * 4 + 1] = u_.y;             \
      gr[Pp][16 + t * 4 + 2] = u_.z; gr[Pp][16 + t * 4 + 3] = u_.w;             \
    }                                                                           \
  } } while (0)

#define LERP_WE(Pp, BUF) do { if (act) {                                        \
    const float wg_ = wS[Pp], om_ = 1.0f - wg_;                                 \
    _Pragma("unroll")                                                           \
    for (int t2 = 0; t2 < 2; ++t2) {                                            \
      bf16x8_t o_;                                                              \
      _Pragma("unroll")                                                         \
      for (int u = 0; u < 8; ++u)                                               \
        o_[u] = (__bf16)(gr[Pp][t2 * 8 + u] * om_ +                             \
                         gr[Pp][16 + t2 * 8 + u] * wg_);                        \
      const int kq_ = se * 2 + t2;                                              \
      *(bf16x8_t*)(&lds[BUF][ble >> 4][kq_ >> 2]                                \
                       [((kq_ & 3) * 16 + (ble & 15)) * 8]) = o_;               \
    }                                                                           \
  } } while (0)

#define ISSUE_B(g1, Ss) do {                                                    \
    const __bf16* pb_ = bg + (size_t)((g1) * 3) * 512;                          \
    _Pragma("unroll")                                                           \
    for (int ks = 0; ks < 3; ++ks) {                                            \
      bB[Ss][ks * 2 + 0] = *(const bf16x8_t*)(pb_ + (size_t)ks * 512);          \
      bB[Ss][ks * 2 + 1] = *(const bf16x8_t*)(pb_ + PS + (size_t)ks * 512);     \
    }                                                                           \
  } while (0)

#define COMPUTE(Pp) do {                                                        \
    _Pragma("unroll")                                                           \
    for (int ks = 0; ks < 3; ++ks) {                                            \
      bf16x8_t a0_ = *(const bf16x8_t*)(&lds[Pp][0][ks][l * 8]);                \
      bf16x8_t a1_ = *(const bf16x8_t*)(&lds[Pp][1][ks][l * 8]);                \
      acc00 = mfma16(a0_, bB[Pp][ks * 2 + 0], acc00);                           \
      acc01 = mfma16(a0_, bB[Pp][ks * 2 + 1], acc01);                           \
      acc10 = mfma16(a1_, bB[Pp][ks * 2 + 0], acc10);                           \
      acc11 = mfma16(a1_, bB[Pp][ks * 2 + 1], acc11);                           \
    }                                                                           \
  } while (0)

  // prologue: 2 gather sets + 1 B set in flight, group 0 staged
  if (is_imu) { ISSUE_GI(0, 0); ISSUE_GI(1, 1); }
  else        { ISSUE_GE(0, 0); ISSUE_GE(1, 1); }
  ISSUE_B(0, 0);
  if (is_imu) LERP_WI(0, 0); else LERP_WE(0, 0);
  __syncthreads();

  for (int gp = 0; gp < (NG + 1) / 2; ++gp) {
    const int g = gp * 2;
    {
      if (g + 2 < NG) { if (is_imu) ISSUE_GI(g + 2, 0); else ISSUE_GE(g + 2, 0); }
      if (g + 1 < NG) ISSUE_B(g + 1, 1);
      COMPUTE(0);
      if (g + 1 < NG) { if (is_imu) LERP_WI(1, 1); else LERP_WE(1, 1); }
      __syncthreads();
    }
    if (g + 1 < NG) {
      if (g + 3 < NG) { if (is_imu) ISSUE_GI(g + 3, 1); else ISSUE_GE(g + 3, 1); }
      if (g + 2 < NG) ISSUE_B(g + 2, 0);
      COMPUTE(1);
      if (g + 2 < NG) { if (is_imu) LERP_WI(0, 0); else LERP_WE(0, 0); }
      __syncthreads();
    }
  }

  // epilogue: C/D col = lane&15, row = (lane>>4)*4 + reg
  const int lh = l >> 4, lr = l & 15;
  float* Pb = P + (size_t)(mt * 32 + lh * 4) * NCOL + nh * 128 + wv * 32 + lr;
#pragma unroll
  for (int jj = 0; jj < 4; ++jj) {
    Pb[(size_t)jj * NCOL] = acc00[jj];
    Pb[(size_t)jj * NCOL + 16] = acc01[jj];
    Pb[(size_t)(16 + jj) * NCOL] = acc10[jj];
    Pb[(size_t)(16 + jj) * NCOL + 16] = acc11[jj];
  }
#undef ISSUE_GI
#undef LERP_WI
#undef ISSUE_GE
#undef LERP_WE
#undef ISSUE_B
#undef COMPUTE
}

// ---------- K2: sum split-K partials + bias -> d_out
__global__ __launch_bounds__(256) void combine_kernel(
    const float* __restrict__ bias, const float* __restrict__ p_imu,
    const float* __restrict__ p_emg, float* __restrict__ out, int B) {
  const int b = blockIdx.x, m = blockIdx.y, j = threadIdx.x;
  const size_t n = (size_t)B * NCOL;
  const size_t o = (size_t)b * NCOL + j;
  if (m == 0) {
    float v = bias[j];
#pragma unroll
    for (int c = 0; c < NCI; ++c) v += p_imu[c * n + o];
    out[o] = v;
  } else {
    out[n + o] = bias[NCOL + j] + p_emg[o] + p_emg[n + o];
  }
}

extern "C" void kernel_launch(void* const* d_in, const int* in_sizes, int n_in,
                              void* d_out, int out_size, void* d_ws, size_t ws_size,
                              hipStream_t stream) {
  const float* x_imu     = (const float*)d_in[0];
  const float* x_emg     = (const float*)d_in[1];
  const int*   lens      = (const int*)d_in[2];
  const float* w_emb_imu = (const float*)d_in[3];
  const float* b_emb_imu = (const float*)d_in[4];
  const float* w_emb_emg = (const float*)d_in[5];
  const float* b_emb_emg = (const float*)d_in[6];
  const float* w_proj    = (const float*)d_in[7];
  const float* b_proj    = (const float*)d_in[8];
  float* out = (float*)d_out;

  const int B = in_sizes[2];
  const int T = in_sizes[0] / (B * CIMU);

  char* ws = (char*)d_ws;
  __bf16* wpk_imu = (__bf16*)ws;  ws += (size_t)NCOL * KIMU * 2;
  __bf16* wpk_emg = (__bf16*)ws;  ws += (size_t)NCOL * KEMG * 2;
  float*  bias    = (float*)ws;   ws += 2 * NCOL * 4;
  float*  bpart   = (float*)ws;   ws += (size_t)2 * NEWL * NCOL * 4;
  float*  p_imu   = (float*)ws;   ws += (size_t)NCI * B * NCOL * 4;
  float*  p_emg   = (float*)ws;   ws += (size_t)NCE * B * NCOL * 4;

  wcomb_kernel<<<dim3(NEWL, 2), 256, 0, stream>>>(
      w_emb_imu, w_emb_emg, b_emb_imu, b_emb_emg, w_proj, wpk_imu, wpk_emg, bpart);
  const int span = B >> 4;                        // 128
  const int nblk = (NCE + NCI) * span + 1;        // 769
  fused_kernel<<<nblk, 256, 0, stream>>>(x_imu, x_emg, lens, wpk_imu, wpk_emg,
                                         b_proj, bpart, p_imu, p_emg, bias, B, T);
  combine_kernel<<<dim3(B, 2), 256, 0, stream>>>(bias, p_imu, p_emg, out, B);
}

// Round 12
// 81.118 us; speedup vs baseline: 1.4003x; 1.0373x over previous
//
#include <hip/hip_runtime.h>

#define NEWL 150
#define EMBD 64
#define NCOL 256
#define CIMU 48
#define CEMG 16

#define KIMU (NEWL * CIMU)  // 7200
#define KEMG (NEWL * CEMG)  // 2400
#define KSTI 225            // total k-steps (32-wide) imu
#define KSTE 75             // total k-steps emg
#define NCI 4               // imu s-chunks (19/19/19/18 groups)
#define NCE 2               // emg s-chunks (13/12 groups)

typedef __bf16 bf16x8_t __attribute__((ext_vector_type(8)));
typedef __bf16 bf16x4_t __attribute__((ext_vector_type(4)));
typedef float f32x4_t __attribute__((ext_vector_type(4)));

__device__ __forceinline__ f32x4_t mfma16(bf16x8_t a, bf16x8_t b, f32x4_t c) {
  return __builtin_amdgcn_mfma_f32_16x16x32_bf16(a, b, c, 0, 0, 0);
}

// ---------- K0: combined weights packed in MFMA B-fragment order + bias partials.
// W_pack[cb][ks][lane=h*16+(col&15)][u]  where k = ks*32 + h*8 + u
template <int C, int KST>
__device__ void wcomb_body(const float* __restrict__ wemb,
                           const float* __restrict__ wreg_src,
                           __bf16* __restrict__ wpk, int s, int j) {
  float wreg[EMBD];
#pragma unroll
  for (int e = 0; e < EMBD; ++e) wreg[e] = wreg_src[(size_t)e * NCOL];
  const int cb = j >> 4, lr = j & 15;
#pragma unroll
  for (int q = 0; q < C / 8; ++q) {
    const int kq = (s * C) / 8 + q;
    const int ks = kq >> 2, h = kq & 3;
    bf16x8_t tv;
#pragma unroll
    for (int u = 0; u < 8; ++u) {
      const float* we = wemb + (q * 8 + u) * EMBD;
      float acc = 0.f;
#pragma unroll
      for (int e = 0; e < EMBD; ++e) acc = fmaf(we[e], wreg[e], acc);
      tv[u] = (__bf16)acc;
    }
    *(bf16x8_t*)(wpk + (((size_t)cb * KST + ks) * 64 + h * 16 + lr) * 8) = tv;
  }
}

__global__ __launch_bounds__(256) void wcomb_kernel(
    const float* __restrict__ w_emb_imu, const float* __restrict__ w_emb_emg,
    const float* __restrict__ b_emb_imu, const float* __restrict__ b_emb_emg,
    const float* __restrict__ w_proj,
    __bf16* __restrict__ wpk_imu, __bf16* __restrict__ wpk_emg,
    float* __restrict__ bpart) {
  const int s = blockIdx.x;   // 0..149
  const int m = blockIdx.y;   // 0 = imu, 1 = emg
  const int j = threadIdx.x;  // output column 0..255
  const float* wp_base = w_proj + (size_t)s * EMBD * NCOL + j;
  const float* be = (m == 0) ? b_emb_imu : b_emb_emg;
  float bacc = 0.f;
#pragma unroll
  for (int e = 0; e < EMBD; ++e) bacc = fmaf(be[e], wp_base[(size_t)e * NCOL], bacc);
  bpart[((size_t)m * NEWL + s) * NCOL + j] = bacc;
  if (m == 0)
    wcomb_body<CIMU, KSTI>(w_emb_imu, wp_base, wpk_imu, s, j);
  else
    wcomb_body<CEMG, KSTE>(w_emb_emg, wp_base, wpk_emg, s, j);
}

// ---------- K1: fused ragged-interp + MFMA GEMM (+ bias-reduce tail block)
// Single-slot pipeline (distance 1): ISSUE_G(p+1) -> COMPUTE(p) ->
// ISSUE_B(p+1) -> LERP(p+1) -> barrier.  Clamped to 128 VGPR for 4 blocks/CU.
__global__ __launch_bounds__(256, 4) void fused_kernel(
    const float* __restrict__ x_imu, const float* __restrict__ x_emg,
    const int* __restrict__ lens,
    const __bf16* __restrict__ wpk_imu, const __bf16* __restrict__ wpk_emg,
    const float* __restrict__ b_proj, const float* __restrict__ bpart,
    float* __restrict__ p_imu, float* __restrict__ p_emg,
    float* __restrict__ bias, int B, int T) {
  const int bid = blockIdx.x;
  const int span = B >> 4;  // blocks per chunk (mtiles*2)
  const int mts = B >> 5;   // 32-row m-tiles
  if (bid == (NCE + NCI) * span) {  // bias tail block
    const int j = threadIdx.x;
#pragma unroll
    for (int m = 0; m < 2; ++m) {
      float acc = b_proj[j];
      for (int s = 0; s < NEWL; ++s) acc += bpart[((size_t)m * NEWL + s) * NCOL + j];
      bias[m * NCOL + j] = acc;
    }
    return;
  }

  __shared__ __bf16 lds[2][2][3][512];  // [buf][row-plane][ks][lane*8]

  const int tid = threadIdx.x;
  const int wv = tid >> 6, l = tid & 63;

  const int cs = bid / span;
  const int r = bid - cs * span;
  const bool is_imu = cs >= NCE;
  const int c = is_imu ? cs - NCE : cs;
  const int nh = r / mts, mt = r - nh * mts;

  // chunk geometry (group = 3 ksteps; imu: 2 s/group, emg: 6 s/group)
  int g0, NG;
  if (is_imu) { g0 = 19 * c; NG = (c < 3) ? 19 : 18; }
  else        { g0 = 13 * c; NG = c ? 12 : 13; }
  const int ks0 = 3 * g0;
  const int sb = is_imu ? 2 * g0 : 6 * g0;

  const __bf16* Wp = is_imu ? wpk_imu : wpk_emg;
  const int KST = is_imu ? KSTI : KSTE;
  float* P = is_imu ? (p_imu + (size_t)c * B * NCOL) : (p_emg + (size_t)c * B * NCOL);

  const size_t PS = (size_t)KST * 512;  // B fragment-plane stride (bf16)
  const __bf16* bg = Wp + ((size_t)(nh * 8 + wv * 2) * KST + ks0) * 512 + l * 8;

  // gather thread mappings
  const int q = tid & 3, sl = (tid >> 2) & 1, bli = tid >> 3;  // imu: 4 thr/(b,s)
  const int ble = tid / 6, se = tid - ble * 6;                 // emg: 1 thr/(b,s), tid<192
  const bool act = is_imu || (tid < 192);
  const int b_g = mt * 32 + (is_imu ? bli : (act ? ble : 0));
  int lenv = 1;
  float scale = 0.f;
  if (act) { lenv = lens[b_g]; scale = (float)lenv * (1.0f / 150.0f); }

  float gr[32];     // single gather slot (imu uses 24, emg 32)
  float wS;         // lerp weight
  bf16x8_t bB[6];   // single B slot (2 planes x 3 ksteps)
  f32x4_t acc00 = {0.f, 0.f, 0.f, 0.f}, acc01 = acc00, acc10 = acc00, acc11 = acc00;

// imu gather, quad-contiguous: lane q reads bytes [t*64+q*16) of both rows.
#define ISSUE_GI(g2) do {                                                       \
    const int s_ = sb + (g2) * 2 + sl;                                          \
    float src_ = fmaxf(((float)s_ + 0.5f) * scale - 0.5f, 0.0f);                \
    int i0_ = min((int)src_, lenv - 1);                                         \
    int i1_ = min(i0_ + 1, lenv - 1);                                           \
    wS = src_ - (float)i0_;                                                     \
    const float* r0_ = x_imu + ((size_t)b_g * T + i0_) * CIMU + q * 4;          \
    const float* r1_ = x_imu + ((size_t)b_g * T + i1_) * CIMU + q * 4;          \
    _Pragma("unroll")                                                           \
    for (int t = 0; t < 3; ++t) {                                               \
      float4 v_ = *(const float4*)(r0_ + t * 16);                               \
      gr[t * 4 + 0] = v_.x; gr[t * 4 + 1] = v_.y;                               \
      gr[t * 4 + 2] = v_.z; gr[t * 4 + 3] = v_.w;                               \
      float4 u_ = *(const float4*)(r1_ + t * 16);                               \
      gr[12 + t * 4 + 0] = u_.x; gr[12 + t * 4 + 1] = u_.y;                     \
      gr[12 + t * 4 + 2] = u_.z; gr[12 + t * 4 + 3] = u_.w;                     \
    }                                                                           \
  } while (0)

// in-lane lerp; all 4 quad threads write distinct bf16x4 pieces.
#define LERP_WI(BUF) do {                                                       \
    const float wg_ = wS, om_ = 1.0f - wg_;                                     \
    _Pragma("unroll")                                                           \
    for (int t = 0; t < 3; ++t) {                                               \
      bf16x4_t o_;                                                              \
      _Pragma("unroll")                                                         \
      for (int u = 0; u < 4; ++u)                                               \
        o_[u] = (__bf16)(gr[t * 4 + u] * om_ + gr[12 + t * 4 + u] * wg_);       \
      const int kq_ = sl * 6 + t * 2 + (q >> 1);                                \
      *(bf16x4_t*)(&lds[BUF][bli >> 4][kq_ >> 2]                                \
                       [((kq_ & 3) * 16 + (bli & 15)) * 8 + (q & 1) * 4]) = o_; \
    }                                                                           \
  } while (0)

#define ISSUE_GE(g2) do { if (act) {                                            \
    const int s_ = sb + (g2) * 6 + se;                                          \
    float src_ = fmaxf(((float)s_ + 0.5f) * scale - 0.5f, 0.0f);                \
    int i0_ = min((int)src_, lenv - 1);                                         \
    int i1_ = min(i0_ + 1, lenv - 1);                                           \
    wS = src_ - (float)i0_;                                                     \
    const float* p0_ = x_emg + ((size_t)b_g * T + i0_) * CEMG;                  \
    const float* p1_ = x_emg + ((size_t)b_g * T + i1_) * CEMG;                  \
    _Pragma("unroll")                                                           \
    for (int t = 0; t < 4; ++t) {                                               \
      float4 v_ = *(const float4*)(p0_ + t * 4);                                \
      gr[t * 4 + 0] = v_.x; gr[t * 4 + 1] = v_.y;                               \
      gr[t * 4 + 2] = v_.z; gr[t * 4 + 3] = v_.w;                               \
      float4 u_ = *(const float4*)(p1_ + t * 4);                                \
      gr[16 + t * 4 + 0] = u_.x; gr[16 + t * 4 + 1] = u_.y;                     \
      gr[16 + t * 4 + 2] = u_.z; gr[16 + t * 4 + 3] = u_.w;                     \
    }                                                                           \
  } } while (0)

#define LERP_WE(BUF) do { if (act) {                                            \
    const float wg_ = wS, om_ = 1.0f - wg_;                                     \
    _Pragma("unroll")                                                           \
    for (int t2 = 0; t2 < 2; ++t2) {                                            \
      bf16x8_t o_;                                                              \
      _Pragma("unroll")                                                         \
      for (int u = 0; u < 8; ++u)                                               \
        o_[u] = (__bf16)(gr[t2 * 8 + u] * om_ + gr[16 + t2 * 8 + u] * wg_);     \
      const int kq_ = se * 2 + t2;                                              \
      *(bf16x8_t*)(&lds[BUF][ble >> 4][kq_ >> 2]                                \
                       [((kq_ & 3) * 16 + (ble & 15)) * 8]) = o_;               \
    }                                                                           \
  } } while (0)

#define ISSUE_B(g1) do {                                                        \
    const __bf16* pb_ = bg + (size_t)((g1) * 3) * 512;                          \
    _Pragma("unroll")                                                           \
    for (int ks = 0; ks < 3; ++ks) {                                            \
      bB[ks * 2 + 0] = *(const bf16x8_t*)(pb_ + (size_t)ks * 512);              \
      bB[ks * 2 + 1] = *(const bf16x8_t*)(pb_ + PS + (size_t)ks * 512);         \
    }                                                                           \
  } while (0)

#define COMPUTE(Pp) do {                                                        \
    _Pragma("unroll")                                                           \
    for (int ks = 0; ks < 3; ++ks) {                                            \
      bf16x8_t a0_ = *(const bf16x8_t*)(&lds[Pp][0][ks][l * 8]);                \
      bf16x8_t a1_ = *(const bf16x8_t*)(&lds[Pp][1][ks][l * 8]);                \
      acc00 = mfma16(a0_, bB[ks * 2 + 0], acc00);                               \
      acc01 = mfma16(a0_, bB[ks * 2 + 1], acc01);                               \
      acc10 = mfma16(a1_, bB[ks * 2 + 0], acc10);                               \
      acc11 = mfma16(a1_, bB[ks * 2 + 1], acc11);                               \
    }                                                                           \
  } while (0)

  // prologue: stage group 0, load B0
  if (is_imu) { ISSUE_GI(0); LERP_WI(0); }
  else        { ISSUE_GE(0); LERP_WE(0); }
  ISSUE_B(0);
  __syncthreads();

  for (int p = 0; p < NG; ++p) {
    const int more = (p + 1 < NG);
    if (more) { if (is_imu) ISSUE_GI(p + 1); else ISSUE_GE(p + 1); }
    COMPUTE(p & 1);
    if (more) ISSUE_B(p + 1);
    if (more) { if (is_imu) LERP_WI((p + 1) & 1); else LERP_WE((p + 1) & 1); }
    __syncthreads();
  }

  // epilogue: C/D col = lane&15, row = (lane>>4)*4 + reg
  const int lh = l >> 4, lr = l & 15;
  float* Pb = P + (size_t)(mt * 32 + lh * 4) * NCOL + nh * 128 + wv * 32 + lr;
#pragma unroll
  for (int jj = 0; jj < 4; ++jj) {
    Pb[(size_t)jj * NCOL] = acc00[jj];
    Pb[(size_t)jj * NCOL + 16] = acc01[jj];
    Pb[(size_t)(16 + jj) * NCOL] = acc10[jj];
    Pb[(size_t)(16 + jj) * NCOL + 16] = acc11[jj];
  }
#undef ISSUE_GI
#undef LERP_WI
#undef ISSUE_GE
#undef LERP_WE
#undef ISSUE_B
#undef COMPUTE
}

// ---------- K2: sum split-K partials + bias -> d_out
__global__ __launch_bounds__(256) void combine_kernel(
    const float* __restrict__ bias, const float* __restrict__ p_imu,
    const float* __restrict__ p_emg, float* __restrict__ out, int B) {
  const int b = blockIdx.x, m = blockIdx.y, j = threadIdx.x;
  const size_t n = (size_t)B * NCOL;
  const size_t o = (size_t)b * NCOL + j;
  if (m == 0) {
    float v = bias[j];
#pragma unroll
    for (int c = 0; c < NCI; ++c) v += p_imu[c * n + o];
    out[o] = v;
  } else {
    out[n + o] = bias[NCOL + j] + p_emg[o] + p_emg[n + o];
  }
}

extern "C" void kernel_launch(void* const* d_in, const int* in_sizes, int n_in,
                              void* d_out, int out_size, void* d_ws, size_t ws_size,
                              hipStream_t stream) {
  const float* x_imu     = (const float*)d_in[0];
  const float* x_emg     = (const float*)d_in[1];
  const int*   lens      = (const int*)d_in[2];
  const float* w_emb_imu = (const float*)d_in[3];
  const float* b_emb_imu = (const float*)d_in[4];
  const float* w_emb_emg = (const float*)d_in[5];
  const float* b_emb_emg = (const float*)d_in[6];
  const float* w_proj    = (const float*)d_in[7];
  const float* b_proj    = (const float*)d_in[8];
  float* out = (float*)d_out;

  const int B = in_sizes[2];
  const int T = in_sizes[0] / (B * CIMU);

  char* ws = (char*)d_ws;
  __bf16* wpk_imu = (__bf16*)ws;  ws += (size_t)NCOL * KIMU * 2;
  __bf16* wpk_emg = (__bf16*)ws;  ws += (size_t)NCOL * KEMG * 2;
  float*  bias    = (float*)ws;   ws += 2 * NCOL * 4;
  float*  bpart   = (float*)ws;   ws += (size_t)2 * NEWL * NCOL * 4;
  float*  p_imu   = (float*)ws;   ws += (size_t)NCI * B * NCOL * 4;
  float*  p_emg   = (float*)ws;   ws += (size_t)NCE * B * NCOL * 4;

  wcomb_kernel<<<dim3(NEWL, 2), 256, 0, stream>>>(
      w_emb_imu, w_emb_emg, b_emb_imu, b_emb_emg, w_proj, wpk_imu, wpk_emg, bpart);
  const int span = B >> 4;                        // 128
  const int nblk = (NCE + NCI) * span + 1;        // 769
  fused_kernel<<<nblk, 256, 0, stream>>>(x_imu, x_emg, lens, wpk_imu, wpk_emg,
                                         b_proj, bpart, p_imu, p_emg, bias, B, T);
  combine_kernel<<<dim3(B, 2), 256, 0, stream>>>(bias, p_imu, p_emg, out, B);
}